// Round 6
// baseline (128.369 us; speedup 1.0000x reference)
//
#include <hip/hip_runtime.h>
#include <math.h>

#define HH 1024
#define WW 1024
#define PADK 15
#define RB 16
#define TPB 512
#define EPSV 1e-5f
#define INV_K2 (1.0f / 961.0f)

__global__ __launch_bounds__(TPB) void lcn_kernel(const float* __restrict__ x,
                                                  float* __restrict__ out) {
    // 8 waves/block, waves 0-3 band A (16 rows), 4-7 band B. Wave owns a
    // 256-col stripe, 4 cols/lane. Per-wave private LDS regions
    // (16 halo | 256 owned | 16 halo, padded to 296). No __syncthreads:
    // all LDS traffic wave-local; DS ops in-order within a wave.
    // Horizontal pass STREAMS the base sum (r4-verified form).
    // NEW vs r4 (single change): next-row update loads are issued at the TOP
    // of the row body and consumed AFTER the store (bit-identical op order).
    __shared__ __align__(16) float sxl[8][296];
    __shared__ __align__(16) float sql[8][296];

    const int blk  = blockIdx.x;
    const int b    = blk >> 5;         // image
    const int pair = blk & 31;         // 32-row pair within image
    const int t    = threadIdx.x;
    const int w    = t >> 6;           // wave id 0..7
    const int l    = t & 63;           // lane
    const int band = w >> 2;           // 0 or 1
    const int wq   = w & 3;            // column quarter
    const int r0   = pair * 32 + band * RB;
    const int wc0  = wq * 256;
    const int c0   = wc0 + l * 4;

    float* __restrict__ sxw = sxl[w];
    float* __restrict__ sqw = sql[w];

    // halo assignment: lanes 0..3 -> left halo float4s, lanes 4..7 -> right
    int hcol = 0;
    const bool hlane = (l < 8);
    if (l < 4)      hcol = wc0 - 16 + 4 * l;
    else if (l < 8) hcol = wc0 + 256 + 4 * (l - 4);
    const bool hvalid = hlane && (hcol >= 0) && (hcol < WW);
    const int  hidx   = (l < 4) ? 4 * l : 272 + 4 * (l - 4);

    const float* __restrict__ img  = x   + (size_t)b * HH * WW;
    float* __restrict__       oimg = out + (size_t)b * HH * WW;

    float4 s   = make_float4(0.f, 0.f, 0.f, 0.f);
    float4 s2  = make_float4(0.f, 0.f, 0.f, 0.f);
    float4 hs  = make_float4(0.f, 0.f, 0.f, 0.f);
    float4 hs2 = make_float4(0.f, 0.f, 0.f, 0.f);

    // --- init vertical sliding sums for output row r0 ---
    {
        int lo = r0 - PADK; if (lo < 0) lo = 0;
        int hi = r0 + PADK;                 // r0 <= 1008 -> hi <= 1023
        for (int r = lo; r <= hi; ++r) {
            const float* rowp = img + (size_t)r * WW;
            float4 v = *reinterpret_cast<const float4*>(rowp + c0);
            s.x  += v.x;       s.y  += v.y;       s.z  += v.z;       s.w  += v.w;
            s2.x += v.x * v.x; s2.y += v.y * v.y; s2.z += v.z * v.z; s2.w += v.w * v.w;
            if (hvalid) {
                float4 hv = *reinterpret_cast<const float4*>(rowp + hcol);
                hs.x  += hv.x;        hs.y  += hv.y;        hs.z  += hv.z;        hs.w  += hv.w;
                hs2.x += hv.x * hv.x; hs2.y += hv.y * hv.y; hs2.z += hv.z * hv.z; hs2.w += hv.w * hv.w;
            }
        }
    }

    for (int i = 0; i < RB; ++i) {
        const int orow = r0 + i;

        // issue current-row center load early (consumed in the pointwise step)
        const float4 xc = *reinterpret_cast<const float4*>(img + (size_t)orow * WW + c0);

        // issue next-row update loads early (consumed after the store)
        float4 pa  = make_float4(0.f, 0.f, 0.f, 0.f);
        float4 pb  = make_float4(0.f, 0.f, 0.f, 0.f);
        float4 pha = make_float4(0.f, 0.f, 0.f, 0.f);
        float4 phb = make_float4(0.f, 0.f, 0.f, 0.f);
        if (i < RB - 1) {
            const int radd = orow + PADK + 1;      // entering row for orow+1
            if (radd < HH) {
                const float* rowp = img + (size_t)radd * WW;
                pa = *reinterpret_cast<const float4*>(rowp + c0);
                if (hvalid) pha = *reinterpret_cast<const float4*>(rowp + hcol);
            }
            const int rsub = orow - PADK;          // leaving row for orow+1
            if (rsub >= 0) {
                const float* rowp = img + (size_t)rsub * WW;
                pb = *reinterpret_cast<const float4*>(rowp + c0);
                if (hvalid) phb = *reinterpret_cast<const float4*>(rowp + hcol);
            }
        }

        // write this wave's vertical sums (owned + halo) to its LDS region
        *reinterpret_cast<float4*>(sxw + 16 + 4 * l) = s;
        *reinterpret_cast<float4*>(sqw + 16 + 4 * l) = s2;
        if (hlane) {
            *reinterpret_cast<float4*>(sxw + hidx) = hs;    // zeros when !hvalid
            *reinterpret_cast<float4*>(sqw + hidx) = hs2;
        }
        // no barrier: DS ops are in-order within a wave

        // --- horizontal 31-window sums, streamed (r4-verified) ---
        // window for owned col q: LDS elems (4l + q+1 .. 4l + q+31)
        // base = elems 4..31 (R1..R7 complete); edges come from R0 / R8.
        float mean0, mean1, mean2, mean3;
        {
            float4 r0v = *reinterpret_cast<const float4*>(sxw + 4 * l);
            float b0 = 0.f, b1 = 0.f;
            #pragma unroll
            for (int m = 1; m < 8; ++m) {
                float4 v = *reinterpret_cast<const float4*>(sxw + 4 * l + 4 * m);
                b0 += (v.x + v.y);
                b1 += (v.z + v.w);
            }
            float4 r8v = *reinterpret_cast<const float4*>(sxw + 4 * l + 32);
            float base = b0 + b1;
            mean0 = (base + ((r0v.y + r0v.z) + r0v.w)) * INV_K2;
            mean1 = (base + ((r0v.z + r0v.w) + r8v.x)) * INV_K2;
            mean2 = (base + ((r0v.w + r8v.x) + r8v.y)) * INV_K2;
            mean3 = (base + ((r8v.x + r8v.y) + r8v.z)) * INV_K2;
        }
        float sq0, sq1, sq2, sq3;
        {
            float4 r0v = *reinterpret_cast<const float4*>(sqw + 4 * l);
            float b0 = 0.f, b1 = 0.f;
            #pragma unroll
            for (int m = 1; m < 8; ++m) {
                float4 v = *reinterpret_cast<const float4*>(sqw + 4 * l + 4 * m);
                b0 += (v.x + v.y);
                b1 += (v.z + v.w);
            }
            float4 r8v = *reinterpret_cast<const float4*>(sqw + 4 * l + 32);
            float base = b0 + b1;
            sq0 = (base + ((r0v.y + r0v.z) + r0v.w)) * INV_K2;
            sq1 = (base + ((r0v.z + r0v.w) + r8v.x)) * INV_K2;
            sq2 = (base + ((r0v.w + r8v.x) + r8v.y)) * INV_K2;
            sq3 = (base + ((r8v.x + r8v.y) + r8v.z)) * INV_K2;
        }

        float4 ro;
        {
            float sd  = sqrtf(fmaxf(sq0 - mean0 * mean0, EPSV));
            float nrm = (xc.x - mean0) * __builtin_amdgcn_rcpf(sd + EPSV);
            ro.x = xc.x * 0.2f + 0.8f / (1.0f + __expf(-0.5f * nrm));
        }
        {
            float sd  = sqrtf(fmaxf(sq1 - mean1 * mean1, EPSV));
            float nrm = (xc.y - mean1) * __builtin_amdgcn_rcpf(sd + EPSV);
            ro.y = xc.y * 0.2f + 0.8f / (1.0f + __expf(-0.5f * nrm));
        }
        {
            float sd  = sqrtf(fmaxf(sq2 - mean2 * mean2, EPSV));
            float nrm = (xc.z - mean2) * __builtin_amdgcn_rcpf(sd + EPSV);
            ro.z = xc.z * 0.2f + 0.8f / (1.0f + __expf(-0.5f * nrm));
        }
        {
            float sd  = sqrtf(fmaxf(sq3 - mean3 * mean3, EPSV));
            float nrm = (xc.w - mean3) * __builtin_amdgcn_rcpf(sd + EPSV);
            ro.w = xc.w * 0.2f + 0.8f / (1.0f + __expf(-0.5f * nrm));
        }
        *reinterpret_cast<float4*>(oimg + (size_t)orow * WW + c0) = ro;

        // --- consume prefetched rows (r4's exact op order: add-block, sub-block) ---
        if (i < RB - 1) {
            s.x  += pa.x;        s.y  += pa.y;        s.z  += pa.z;        s.w  += pa.w;
            s2.x += pa.x * pa.x; s2.y += pa.y * pa.y; s2.z += pa.z * pa.z; s2.w += pa.w * pa.w;
            hs.x  += pha.x;        hs.y  += pha.y;        hs.z  += pha.z;        hs.w  += pha.w;
            hs2.x += pha.x * pha.x; hs2.y += pha.y * pha.y; hs2.z += pha.z * pha.z; hs2.w += pha.w * pha.w;

            s.x  -= pb.x;        s.y  -= pb.y;        s.z  -= pb.z;        s.w  -= pb.w;
            s2.x -= pb.x * pb.x; s2.y -= pb.y * pb.y; s2.z -= pb.z * pb.z; s2.w -= pb.w * pb.w;
            hs.x  -= phb.x;        hs.y  -= phb.y;        hs.z  -= phb.z;        hs.w  -= phb.w;
            hs2.x -= phb.x * phb.x; hs2.y -= phb.y * phb.y; hs2.z -= phb.z * phb.z; hs2.w -= phb.w * phb.w;
        }
    }
}

extern "C" void kernel_launch(void* const* d_in, const int* in_sizes, int n_in,
                              void* d_out, int out_size, void* d_ws, size_t ws_size,
                              hipStream_t stream) {
    const float* xin = (const float*)d_in[0];
    float* out = (float*)d_out;
    const int B = in_sizes[0] / (HH * WW);   // 32
    dim3 grid(B * 32);                       // 1024 blocks x 8 waves
    dim3 block(TPB);
    hipLaunchKernelGGL(lcn_kernel, grid, block, 0, stream, xin, out);
}